// Round 1
// baseline (937.603 us; speedup 1.0000x reference)
//
#include <hip/hip_runtime.h>

typedef unsigned short u16;
typedef unsigned int u32;
typedef __attribute__((ext_vector_type(8))) short short8;
typedef __attribute__((ext_vector_type(4))) float floatx4;

#define MFMA16(A,B,C) __builtin_amdgcn_mfma_f32_16x16x32_bf16((A),(B),(C),0,0,0)

// B=4, T=1024, H=16, D=64; BH=64; rows (b,t,h) = 65536 per side.
// out[0] = true softmax map, out[1] = pred map; each B*T*H*T = 67108864 f32.

__device__ __forceinline__ u16 f2bf(float f){
  u32 u = __float_as_uint(f);
  u32 r = (u + 0x7fffu + ((u >> 16) & 1u)) >> 16;
  return (u16)r;
}
__device__ __forceinline__ float bf2f(u16 h){
  return __uint_as_float(((u32)h) << 16);
}
__device__ __forceinline__ short8 ld8(const u16* p){
  return *(const short8*)p;
}

// ---------------- Kernel A: feature map + bf16 hi/lo split ----------------
// 1 thread per (b,t,h) row; gid<65536 -> q, else k.
// Writes (layout [BH][T][...]): qh/ql (q/8 split, bf16 64), kh/kl (k split),
// phiq/phik (bf16 128 = [exp(y), exp(-y)]).
__global__ __launch_bounds__(256) void featmap_kernel(
    const float* __restrict__ q, const float* __restrict__ k,
    const float* __restrict__ Wq, const float* __restrict__ bq,
    const float* __restrict__ Wk, const float* __restrict__ bk,
    u16* __restrict__ qh, u16* __restrict__ ql,
    u16* __restrict__ kh, u16* __restrict__ kl,
    u16* __restrict__ phiq, u16* __restrict__ phik) {
  u32 gid = blockIdx.x * 256u + threadIdx.x;
  bool is_k = gid >= 65536u;
  u32 r = is_k ? (gid - 65536u) : gid;
  const float* __restrict__ x = (is_k ? k : q) + (size_t)r * 64u;
  const float* __restrict__ W = is_k ? Wk : Wq;
  const float* __restrict__ bias = is_k ? bk : bq;
  u32 b = r >> 14, t = (r >> 4) & 1023u, h = r & 15u;
  u32 orow = (b * 16u + h) * 1024u + t;

  float xv[64];
#pragma unroll
  for (int i = 0; i < 16; i++) {
    float4 v = ((const float4*)x)[i];
    xv[4 * i + 0] = v.x; xv[4 * i + 1] = v.y;
    xv[4 * i + 2] = v.z; xv[4 * i + 3] = v.w;
  }

  // split store (q gets the 1/sqrt(D)=1/8 scale folded in)
  float scale = is_k ? 1.0f : 0.125f;
  u16* hdst = (is_k ? kh : qh) + (size_t)orow * 64u;
  u16* ldst = (is_k ? kl : ql) + (size_t)orow * 64u;
#pragma unroll
  for (int c = 0; c < 8; c++) {
    u16 hi[8] __attribute__((aligned(16)));
    u16 lo[8] __attribute__((aligned(16)));
#pragma unroll
    for (int j = 0; j < 8; j++) {
      float xs = xv[c * 8 + j] * scale;
      u16 hb = f2bf(xs);
      hi[j] = hb;
      lo[j] = f2bf(xs - bf2f(hb));
    }
    ((uint4*)hdst)[c] = *(const uint4*)hi;
    ((uint4*)ldst)[c] = *(const uint4*)lo;
  }

  // y = x @ W^T + b ; phi = [exp(y), exp(-y)]
  u16* pdst = (is_k ? phik : phiq) + (size_t)orow * 128u;
#pragma unroll
  for (int c = 0; c < 4; c++) {
    float accs[16];
#pragma unroll
    for (int i = 0; i < 16; i++) accs[i] = bias[c * 16 + i];
#pragma unroll
    for (int d = 0; d < 64; d++) {
      float xd = xv[d];
#pragma unroll
      for (int i = 0; i < 16; i++) accs[i] += xd * W[(c * 16 + i) * 64 + d];
    }
    u16 pl[16] __attribute__((aligned(16)));
    u16 pm[16] __attribute__((aligned(16)));
#pragma unroll
    for (int i = 0; i < 16; i++) {
      pl[i] = f2bf(__expf(accs[i]));
      pm[i] = f2bf(__expf(-accs[i]));
    }
    ((uint4*)pdst)[2 * c + 0] = ((const uint4*)pl)[0];
    ((uint4*)pdst)[2 * c + 1] = ((const uint4*)pl)[1];
    ((uint4*)(pdst + 64))[2 * c + 0] = ((const uint4*)pm)[0];
    ((uint4*)(pdst + 64))[2 * c + 1] = ((const uint4*)pm)[1];
  }
}

// ---------------- Kernel B: column-sum of phik per (b,h) ----------------
__global__ __launch_bounds__(128) void colsum_kernel(
    const u16* __restrict__ phik, float* __restrict__ colsum) {
  int bh = blockIdx.x;
  int e = threadIdx.x; // 0..127
  const u16* p = phik + (size_t)bh * 1024u * 128u + e;
  float s = 0.f;
#pragma unroll 8
  for (int t = 0; t < 1024; t++) s += bf2f(p[(size_t)t * 128u]);
  colsum[bh * 128 + e] = s;
}

// ---------------- Kernel C (fused): scores + Z + both normalized maps ------
// Transposed MFMA (A=K-side, B=Q-side): D[row=(quad*4+r)=k-col][col=n16=q-row].
// Each lane holds 4 consecutive k-columns of ONE q-row -> dwordx4 stores and
// register-resident exp(scores) for the whole 16-row strip (pt[64]).
// grid = 64 bh * 64 strips(16 rows); 4 waves split the 1024 k-cols.
__global__ __launch_bounds__(256) void fused_kernel(
    const u16* __restrict__ qh, const u16* __restrict__ ql,
    const u16* __restrict__ kh, const u16* __restrict__ kl,
    const u16* __restrict__ phiq, const u16* __restrict__ phik,
    const float* __restrict__ colsum, float* __restrict__ out) {
  int bh = blockIdx.x >> 6, strip = blockIdx.x & 63;
  int tid = threadIdx.x, w = tid >> 6, lane = tid & 63, quad = lane >> 4, n16 = lane & 15;
  u32 base = (u32)bh * 1024u;

  __shared__ float cs[128];
  __shared__ float rzp_s[16];
  __shared__ float zb[4][16];

  if (tid < 128) cs[tid] = colsum[bh * 128 + tid];
  __syncthreads();

  // Zpred for the strip's 16 rows: thread -> (row=tid>>4, seg=tid&15)
  {
    int row = tid >> 4, seg = tid & 15;
    u32 grow = base + strip * 16u + (u32)row;
    short8 v = ld8(phiq + (size_t)grow * 128u + seg * 8);
    float p = 0.f;
#pragma unroll
    for (int j = 0; j < 8; j++) p += bf2f((u16)v[j]) * cs[seg * 8 + j];
#pragma unroll
    for (int off = 1; off < 16; off <<= 1) p += __shfl_xor(p, off);
    if (seg == 0) rzp_s[row] = 1.f / p;
  }

  // persistent Q-side fragments (B-operand), q-row = n16
  u32 qrow = base + strip * 16u + n16;
  short8 bqh[2], bql[2], bpq[4];
#pragma unroll
  for (int ks = 0; ks < 2; ks++) {
    bqh[ks] = ld8(qh + (size_t)qrow * 64u + ks * 32u + quad * 8u);
    bql[ks] = ld8(ql + (size_t)qrow * 64u + ks * 32u + quad * 8u);
  }
#pragma unroll
  for (int ks = 0; ks < 4; ks++)
    bpq[ks] = ld8(phiq + (size_t)qrow * 128u + ks * 32u + quad * 8u);

  __syncthreads();
  float rzp = rzp_s[n16];

  // per-lane output row base: t = strip*16 + n16
  u32 bb = (u32)bh >> 4, hh = (u32)bh & 15u;
  u32 t = strip * 16u + n16;
  float* out0 = out + ((size_t)(bb * 1024u + t) * 16u + hh) * 1024u;
  float* out1 = out0 + 67108864u;

  float pt[64];
#pragma unroll
  for (int ct = 0; ct < 16; ct++) {
    u32 col = base + (u32)(w * 16 + ct) * 16u + n16;
    const u16* kp = kh + (size_t)col * 64u + quad * 8u;
    const u16* lp = kl + (size_t)col * 64u + quad * 8u;
    const u16* pp = phik + (size_t)col * 128u + quad * 8u;
    short8 b0 = ld8(kp), b1 = ld8(kp + 32), c0 = ld8(lp), c1 = ld8(lp + 32);
    short8 p0 = ld8(pp), p1 = ld8(pp + 32), p2 = ld8(pp + 64), p3 = ld8(pp + 96);
    floatx4 acc = {0.f, 0.f, 0.f, 0.f};
    acc = MFMA16(b0, bqh[0], acc);
    acc = MFMA16(b1, bqh[1], acc);
    acc = MFMA16(c0, bqh[0], acc);
    acc = MFMA16(c1, bqh[1], acc);
    acc = MFMA16(b0, bql[0], acc);
    acc = MFMA16(b1, bql[1], acc);
    floatx4 ap = {0.f, 0.f, 0.f, 0.f};
    ap = MFMA16(p0, bpq[0], ap);
    ap = MFMA16(p1, bpq[1], ap);
    ap = MFMA16(p2, bpq[2], ap);
    ap = MFMA16(p3, bpq[3], ap);
#pragma unroll
    for (int r = 0; r < 4; r++) pt[ct * 4 + r] = __expf(acc[r]);
    float4 ov;
    ov.x = ap[0] * rzp; ov.y = ap[1] * rzp;
    ov.z = ap[2] * rzp; ov.w = ap[3] * rzp;
    *(float4*)(out1 + (u32)(w * 16 + ct) * 16u + quad * 4u) = ov;
  }

  // Ztrue: per-lane partial (all 64 pt belong to q-row n16), reduce quads+waves
  float s = 0.f;
#pragma unroll
  for (int i = 0; i < 64; i++) s += pt[i];
  s += __shfl_xor(s, 16);
  s += __shfl_xor(s, 32);
  if (lane < 16) zb[w][lane] = s;
  __syncthreads();
  float rzt = 1.f / (zb[0][n16] + zb[1][n16] + zb[2][n16] + zb[3][n16]);

#pragma unroll
  for (int ct = 0; ct < 16; ct++) {
    float4 ov;
    ov.x = pt[ct * 4 + 0] * rzt; ov.y = pt[ct * 4 + 1] * rzt;
    ov.z = pt[ct * 4 + 2] * rzt; ov.w = pt[ct * 4 + 3] * rzt;
    *(float4*)(out0 + (u32)(w * 16 + ct) * 16u + quad * 4u) = ov;
  }
}

extern "C" void kernel_launch(void* const* d_in, const int* in_sizes, int n_in,
                              void* d_out, int out_size, void* d_ws, size_t ws_size,
                              hipStream_t stream) {
  const float* q  = (const float*)d_in[0];
  const float* k  = (const float*)d_in[1];
  const float* Wq = (const float*)d_in[2];
  const float* bq = (const float*)d_in[3];
  const float* Wk = (const float*)d_in[4];
  const float* bk = (const float*)d_in[5];
  unsigned char* ws = (unsigned char*)d_ws;
  // ws layout (bytes): qh 8M | ql 8M | kh 8M | kl 8M | phiq 16M | phik 16M |
  //                    colsum 32K   (total ~64 MB)
  u16* qh   = (u16*)(ws + (0ull  << 20));
  u16* ql   = (u16*)(ws + (8ull  << 20));
  u16* kh   = (u16*)(ws + (16ull << 20));
  u16* kl   = (u16*)(ws + (24ull << 20));
  u16* phiq = (u16*)(ws + (32ull << 20));
  u16* phik = (u16*)(ws + (48ull << 20));
  float* colsum = (float*)(ws + (64ull << 20));
  float* out = (float*)d_out;

  hipLaunchKernelGGL(featmap_kernel, dim3(512), dim3(256), 0, stream,
                     q, k, Wq, bq, Wk, bk, qh, ql, kh, kl, phiq, phik);
  hipLaunchKernelGGL(colsum_kernel, dim3(64), dim3(128), 0, stream, phik, colsum);
  hipLaunchKernelGGL(fused_kernel, dim3(4096), dim3(256), 0, stream,
                     qh, ql, kh, kl, phiq, phik, colsum, out);
}

// Round 2
// 936.550 us; speedup vs baseline: 1.0011x; 1.0011x over previous
//
#include <hip/hip_runtime.h>

typedef unsigned short u16;
typedef unsigned int u32;
typedef __attribute__((ext_vector_type(8))) short short8;
typedef __attribute__((ext_vector_type(4))) float floatx4;

#define MFMA16(A,B,C) __builtin_amdgcn_mfma_f32_16x16x32_bf16((A),(B),(C),0,0,0)

// B=4, T=1024, H=16, D=64; BH=64; rows (b,t,h) = 65536 per side.
// out[0] = true softmax map, out[1] = pred map; each B*T*H*T = 67108864 f32.

__device__ __forceinline__ u16 f2bf(float f){
  u32 u = __float_as_uint(f);
  u32 r = (u + 0x7fffu + ((u >> 16) & 1u)) >> 16;
  return (u16)r;
}
__device__ __forceinline__ float bf2f(u16 h){
  return __uint_as_float(((u32)h) << 16);
}
__device__ __forceinline__ short8 ld8(const u16* p){
  return *(const short8*)p;
}

// ---------------- Kernel A: feature map + bf16 hi/lo split ----------------
// t-fastest thread order: consecutive threads handle consecutive t of one
// (b,h) row -> output writes (layout [BH][T][...]) are dense 8-16KB spans
// per wave; the scatter moves to the input-read side (latency-hideable).
// gid<65536 -> q, else k. Also zeroes colsum (stream-ordered before colsum).
__global__ __launch_bounds__(256) void featmap_kernel(
    const float* __restrict__ q, const float* __restrict__ k,
    const float* __restrict__ Wq, const float* __restrict__ bq,
    const float* __restrict__ Wk, const float* __restrict__ bk,
    u16* __restrict__ qh, u16* __restrict__ ql,
    u16* __restrict__ kh, u16* __restrict__ kl,
    u16* __restrict__ phiq, u16* __restrict__ phik,
    float* __restrict__ colsum) {
  u32 gid = blockIdx.x * 256u + threadIdx.x;
  if (gid < 8192u) colsum[gid] = 0.f;
  bool is_k = gid >= 65536u;
  u32 r = is_k ? (gid - 65536u) : gid;
  u32 t = r & 1023u, bh = r >> 10;
  u32 b = bh >> 4, h = bh & 15u;
  const float* __restrict__ x =
      (is_k ? k : q) + ((size_t)(b * 1024u + t) * 16u + h) * 64u;
  const float* __restrict__ W = is_k ? Wk : Wq;
  const float* __restrict__ bias = is_k ? bk : bq;
  u32 orow = bh * 1024u + t;

  float xv[64];
#pragma unroll
  for (int i = 0; i < 16; i++) {
    float4 v = ((const float4*)x)[i];
    xv[4 * i + 0] = v.x; xv[4 * i + 1] = v.y;
    xv[4 * i + 2] = v.z; xv[4 * i + 3] = v.w;
  }

  // split store (q gets the 1/sqrt(D)=1/8 scale folded in)
  float scale = is_k ? 1.0f : 0.125f;
  u16* hdst = (is_k ? kh : qh) + (size_t)orow * 64u;
  u16* ldst = (is_k ? kl : ql) + (size_t)orow * 64u;
#pragma unroll
  for (int c = 0; c < 8; c++) {
    u16 hi[8] __attribute__((aligned(16)));
    u16 lo[8] __attribute__((aligned(16)));
#pragma unroll
    for (int j = 0; j < 8; j++) {
      float xs = xv[c * 8 + j] * scale;
      u16 hb = f2bf(xs);
      hi[j] = hb;
      lo[j] = f2bf(xs - bf2f(hb));
    }
    ((uint4*)hdst)[c] = *(const uint4*)hi;
    ((uint4*)ldst)[c] = *(const uint4*)lo;
  }

  // y = x @ W^T + b ; phi = [exp(y), exp(-y)]
  u16* pdst = (is_k ? phik : phiq) + (size_t)orow * 128u;
#pragma unroll
  for (int c = 0; c < 4; c++) {
    float accs[16];
#pragma unroll
    for (int i = 0; i < 16; i++) accs[i] = bias[c * 16 + i];
#pragma unroll
    for (int d = 0; d < 64; d++) {
      float xd = xv[d];
#pragma unroll
      for (int i = 0; i < 16; i++) accs[i] += xd * W[(c * 16 + i) * 64 + d];
    }
    u16 pl[16] __attribute__((aligned(16)));
    u16 pm[16] __attribute__((aligned(16)));
#pragma unroll
    for (int i = 0; i < 16; i++) {
      pl[i] = f2bf(__expf(accs[i]));
      pm[i] = f2bf(__expf(-accs[i]));
    }
    ((uint4*)pdst)[2 * c + 0] = ((const uint4*)pl)[0];
    ((uint4*)pdst)[2 * c + 1] = ((const uint4*)pl)[1];
    ((uint4*)(pdst + 64))[2 * c + 0] = ((const uint4*)pm)[0];
    ((uint4*)(pdst + 64))[2 * c + 1] = ((const uint4*)pm)[1];
  }
}

// ---------------- Kernel B: column-sum of phik per (b,h) ----------------
// 8 t-chunks per bh (512 blocks total), atomicAdd partials into colsum.
__global__ __launch_bounds__(128) void colsum_kernel(
    const u16* __restrict__ phik, float* __restrict__ colsum) {
  int bh = blockIdx.x >> 3, chunk = blockIdx.x & 7;
  int e = threadIdx.x; // 0..127
  const u16* p = phik + (size_t)bh * 131072u + (size_t)chunk * 16384u + e;
  float s = 0.f;
#pragma unroll 8
  for (int t = 0; t < 128; t++) s += bf2f(p[(size_t)t * 128u]);
  atomicAdd(&colsum[bh * 128 + e], s);
}

// ---------------- Kernel C (fused): scores + Z + both normalized maps ------
// Transposed MFMA (A=K-side, B=Q-side): lane(quad,n16) reg r holds
// score[q=strip*16+n16][k=ctg*16+quad*4+r].
// 16 waves per block, 4 ct-iterations per wave -> pt[16] per lane (no spill).
// grid = 64 bh * 64 strips(16 rows), 1024 threads.
__global__ __launch_bounds__(1024) void fused_kernel(
    const u16* __restrict__ qh, const u16* __restrict__ ql,
    const u16* __restrict__ kh, const u16* __restrict__ kl,
    const u16* __restrict__ phiq, const u16* __restrict__ phik,
    const float* __restrict__ colsum, float* __restrict__ out) {
  int bh = blockIdx.x >> 6, strip = blockIdx.x & 63;
  int tid = threadIdx.x, w = tid >> 6, lane = tid & 63, quad = lane >> 4, n16 = lane & 15;
  u32 base = (u32)bh * 1024u;

  __shared__ float cs[128];
  __shared__ float rzp_s[16];
  __shared__ float zb[16][16];

  if (tid < 128) cs[tid] = colsum[bh * 128 + tid];
  __syncthreads();

  // Zpred for the strip's 16 rows: threads 0..255 -> (row=tid>>4, seg=tid&15)
  if (tid < 256) {
    int row = tid >> 4, seg = tid & 15;
    u32 grow = base + strip * 16u + (u32)row;
    short8 v = ld8(phiq + (size_t)grow * 128u + seg * 8);
    float p = 0.f;
#pragma unroll
    for (int j = 0; j < 8; j++) p += bf2f((u16)v[j]) * cs[seg * 8 + j];
#pragma unroll
    for (int off = 1; off < 16; off <<= 1) p += __shfl_xor(p, off);
    if (seg == 0) rzp_s[row] = 1.f / p;
  }

  // persistent Q-side fragments (B-operand), q-row = n16
  u32 qrow = base + strip * 16u + n16;
  short8 bqh[2], bql[2], bpq[4];
#pragma unroll
  for (int ks = 0; ks < 2; ks++) {
    bqh[ks] = ld8(qh + (size_t)qrow * 64u + ks * 32u + quad * 8u);
    bql[ks] = ld8(ql + (size_t)qrow * 64u + ks * 32u + quad * 8u);
  }
#pragma unroll
  for (int ks = 0; ks < 4; ks++)
    bpq[ks] = ld8(phiq + (size_t)qrow * 128u + ks * 32u + quad * 8u);

  __syncthreads();
  float rzp = rzp_s[n16];

  // per-lane output row base: t = strip*16 + n16
  u32 bb = (u32)bh >> 4, hh = (u32)bh & 15u;
  u32 t = strip * 16u + n16;
  float* out0 = out + ((size_t)(bb * 1024u + t) * 16u + hh) * 1024u;
  float* out1 = out0 + 67108864u;

  float pt[16];
#pragma unroll
  for (int ct = 0; ct < 4; ct++) {
    u32 ctg = (u32)(w * 4 + ct);
    u32 col = base + ctg * 16u + n16;
    const u16* kp = kh + (size_t)col * 64u + quad * 8u;
    const u16* lp = kl + (size_t)col * 64u + quad * 8u;
    const u16* pp = phik + (size_t)col * 128u + quad * 8u;
    short8 b0 = ld8(kp), b1 = ld8(kp + 32), c0 = ld8(lp), c1 = ld8(lp + 32);
    short8 p0 = ld8(pp), p1 = ld8(pp + 32), p2 = ld8(pp + 64), p3 = ld8(pp + 96);
    floatx4 acc = {0.f, 0.f, 0.f, 0.f};
    acc = MFMA16(b0, bqh[0], acc);
    acc = MFMA16(b1, bqh[1], acc);
    acc = MFMA16(c0, bqh[0], acc);
    acc = MFMA16(c1, bqh[1], acc);
    acc = MFMA16(b0, bql[0], acc);
    acc = MFMA16(b1, bql[1], acc);
    floatx4 ap = {0.f, 0.f, 0.f, 0.f};
    ap = MFMA16(p0, bpq[0], ap);
    ap = MFMA16(p1, bpq[1], ap);
    ap = MFMA16(p2, bpq[2], ap);
    ap = MFMA16(p3, bpq[3], ap);
#pragma unroll
    for (int r = 0; r < 4; r++) pt[ct * 4 + r] = __expf(acc[r]);
    float4 ov;
    ov.x = ap[0] * rzp; ov.y = ap[1] * rzp;
    ov.z = ap[2] * rzp; ov.w = ap[3] * rzp;
    *(float4*)(out1 + ctg * 16u + quad * 4u) = ov;
  }

  // Ztrue: per-lane partial (all 16 pt belong to q-row n16);
  // reduce over quads (shfl) then over the 16 waves (LDS).
  float s = 0.f;
#pragma unroll
  for (int i = 0; i < 16; i++) s += pt[i];
  s += __shfl_xor(s, 16);
  s += __shfl_xor(s, 32);
  if (lane < 16) zb[w][lane] = s;
  __syncthreads();
  float zt = 0.f;
#pragma unroll
  for (int w2 = 0; w2 < 16; w2++) zt += zb[w2][n16];
  float rzt = 1.f / zt;

#pragma unroll
  for (int ct = 0; ct < 4; ct++) {
    u32 ctg = (u32)(w * 4 + ct);
    float4 ov;
    ov.x = pt[ct * 4 + 0] * rzt; ov.y = pt[ct * 4 + 1] * rzt;
    ov.z = pt[ct * 4 + 2] * rzt; ov.w = pt[ct * 4 + 3] * rzt;
    *(float4*)(out0 + ctg * 16u + quad * 4u) = ov;
  }
}

extern "C" void kernel_launch(void* const* d_in, const int* in_sizes, int n_in,
                              void* d_out, int out_size, void* d_ws, size_t ws_size,
                              hipStream_t stream) {
  const float* q  = (const float*)d_in[0];
  const float* k  = (const float*)d_in[1];
  const float* Wq = (const float*)d_in[2];
  const float* bq = (const float*)d_in[3];
  const float* Wk = (const float*)d_in[4];
  const float* bk = (const float*)d_in[5];
  unsigned char* ws = (unsigned char*)d_ws;
  // ws layout (bytes): qh 8M | ql 8M | kh 8M | kl 8M | phiq 16M | phik 16M |
  //                    colsum 32K   (total ~64 MB)
  u16* qh   = (u16*)(ws + (0ull  << 20));
  u16* ql   = (u16*)(ws + (8ull  << 20));
  u16* kh   = (u16*)(ws + (16ull << 20));
  u16* kl   = (u16*)(ws + (24ull << 20));
  u16* phiq = (u16*)(ws + (32ull << 20));
  u16* phik = (u16*)(ws + (48ull << 20));
  float* colsum = (float*)(ws + (64ull << 20));
  float* out = (float*)d_out;

  hipLaunchKernelGGL(featmap_kernel, dim3(512), dim3(256), 0, stream,
                     q, k, Wq, bq, Wk, bk, qh, ql, kh, kl, phiq, phik, colsum);
  hipLaunchKernelGGL(colsum_kernel, dim3(512), dim3(128), 0, stream, phik, colsum);
  hipLaunchKernelGGL(fused_kernel, dim3(4096), dim3(1024), 0, stream,
                     qh, ql, kh, kl, phiq, phik, colsum, out);
}